// Round 3
// baseline (644.784 us; speedup 1.0000x reference)
//
#include <hip/hip_runtime.h>
#include <cmath>
#include <cstdint>
#include <cstddef>

#define NT 17
#define NP 45
#define CH 8
// B=64, S=512, H=768

__device__ __forceinline__ float rlane(float v, int k) {
    return __int_as_float(__builtin_amdgcn_readlane(__float_as_int(v), k));
}

// ---------------------------------------------------------------------------
// Kernel 1: logits = hidden @ [W_tag | W_pos] + bias   (f32 vector GEMM)
//
// Col-mapped, LDS-free, barrier-free: lane = output column (62 real, 64
// padded); each wave owns 8 rows x full K. Round-2 lesson: hidden via s_load
// stalls (SMEM is lgkmcnt-unordered -> no cross-iteration pipelining). Fix:
// launder the hidden pointer through ds_bpermute so the compiler cannot
// prove it uniform -> hidden loads become vmcnt-counted global_load_dwordx4
// (uniform address = one 64B txn, broadcast return; L1 absorbs the 4x line
// reuse), explicitly double-buffered so one full load generation is always
// in flight under the FMA block. W[k][lane] is a per-lane dword load
// (190 KB, L2-hot). Accumulation is a single fmaf chain in strictly
// ascending k with bias added last -- bitwise identical to all previous
// versions, so downstream argmax/losses are unchanged.
// ---------------------------------------------------------------------------
__global__ __launch_bounds__(256) void gemm_logits(
    const float* __restrict__ hidden, const float* __restrict__ Wt,
    const float* __restrict__ bt, const float* __restrict__ Wp,
    const float* __restrict__ bp, float* __restrict__ tagL,
    float* __restrict__ posL)
{
    const int lane = threadIdx.x & 63;
    const int wid  = threadIdx.x >> 6;
    const int c = (lane < 62) ? lane : 61;          // clamp pad lanes
    const bool isTag = (c < NT);
    const float* wbase = isTag ? (Wt + c) : (Wp + (c - NT));
    const int wstride = isTag ? NT : NP;
    const float bias = isTag ? bt[c] : bp[c - NT];

    const int row0 = blockIdx.x * 32 + wid * 8;

    // Opaque (VGPR-carried) copy of the hidden pointer: ds_bpermute(0, x)
    // broadcasts lane 0's value; numerically identical, but the compiler
    // can no longer prove uniformity -> loads stay on the VMEM pipe.
    uint64_t hb = (uint64_t)(uintptr_t)hidden;
    uint32_t hlo = (uint32_t)__builtin_amdgcn_ds_bpermute(0, (int)(uint32_t)hb);
    uint32_t hhi = (uint32_t)__builtin_amdgcn_ds_bpermute(0, (int)(uint32_t)(hb >> 32));
    const float* hvp = (const float*)(uintptr_t)(((uint64_t)hhi << 32) | hlo);
    const float* h0 = hvp + (size_t)row0 * 768;

    float acc[8];
#pragma unroll
    for (int r = 0; r < 8; ++r) acc[r] = 0.f;

    float4 hv[8], hn[8];
    float wv[4], wn[4];
#pragma unroll
    for (int r = 0; r < 8; ++r) hv[r] = *(const float4*)(h0 + r * 768);
#pragma unroll
    for (int j = 0; j < 4; ++j) wv[j] = wbase[(size_t)j * wstride];

#pragma unroll 2
    for (int kc = 0; kc < 768; kc += 4) {
        if (kc + 4 < 768) {
#pragma unroll
            for (int r = 0; r < 8; ++r)
                hn[r] = *(const float4*)(h0 + r * 768 + kc + 4);
#pragma unroll
            for (int j = 0; j < 4; ++j)
                wn[j] = wbase[(size_t)(kc + 4 + j) * wstride];
        }
#pragma unroll
        for (int r = 0; r < 8; ++r) {
            acc[r] = fmaf(hv[r].x, wv[0], acc[r]);
            acc[r] = fmaf(hv[r].y, wv[1], acc[r]);
            acc[r] = fmaf(hv[r].z, wv[2], acc[r]);
            acc[r] = fmaf(hv[r].w, wv[3], acc[r]);
        }
#pragma unroll
        for (int r = 0; r < 8; ++r) hv[r] = hn[r];
#pragma unroll
        for (int j = 0; j < 4; ++j) wv[j] = wn[j];
    }

    if (lane < 62) {
#pragma unroll
        for (int r = 0; r < 8; ++r) {
            float v = acc[r] + bias;
            size_t row = (size_t)row0 + r;
            if (isTag) tagL[row * NT + c] = v;
            else       posL[row * NP + (c - NT)] = v;
        }
    }
}

// ---------------------------------------------------------------------------
// Kernel 2: the four CRF scans. One wave per (b, role); 256 blocks x 64 thr.
// All-to-all broadcast of the state vector via v_readlane (compile-time lane
// indices); accumulation order kept EXACTLY as the original LDS version so
// results are bitwise unchanged. NLL runs in LINEAR space (f = exp(e)
// precomputed off-chain per chunk; exact power-of-2 rescale per chunk).
// ---------------------------------------------------------------------------
template <int T, int PAD>
__device__ void nll_scan(int b,
    const float* __restrict__ logits, const int* __restrict__ mask,
    const int* __restrict__ targ, const float* __restrict__ start,
    const float* __restrict__ trans, const float* __restrict__ endv,
    float* __restrict__ den, float* __restrict__ num)
{
    const int lane = threadIdx.x;
    const int jj = (lane < T) ? lane : (T - 1);
    float Ecol[PAD];
#pragma unroll
    for (int i = 0; i < PAD; ++i) Ecol[i] = (i < T) ? __expf(trans[i * T + jj]) : 0.f;
    const float esjj = __expf(start[jj]);
    const float* eptr = logits + (size_t)b * 512 * T + jj;
    const int* mptr = mask + b * 512;

    float eb[CH], en[CH], fb[CH];
    int mb, mn = 0;
#pragma unroll
    for (int k = 0; k < CH; ++k) { eb[k] = eptr[k * T]; en[k] = 0.f; }
    mb = mptr[lane & (CH - 1)];

    float a = 0.f;
    int excorr = 0;
    for (int c = 0; c < 64; ++c) {
        unsigned long long kb = __ballot(mb > 0);
        if (c < 63) {
            const float* ep2 = eptr + (c + 1) * CH * T;
#pragma unroll
            for (int k = 0; k < CH; ++k) en[k] = ep2[k * T];
            mn = mptr[(c + 1) * CH + (lane & (CH - 1))];
        }
#pragma unroll
        for (int k = 0; k < CH; ++k) fb[k] = __expf(eb[k]);   // off-chain
#pragma unroll
        for (int s = 0; s < CH; ++s) {
            // readlane broadcast of a; lanes >= T hold a duplicate of column
            // T-1 and Ecol there is 0, so fma contributes exactly 0.
            float d0 = 0.f, d1 = 0.f, d2 = 0.f, d3 = 0.f;
#pragma unroll
            for (int q = 0; q < PAD / 4; ++q) {
                d0 = fmaf(rlane(a, 4 * q + 0), Ecol[4 * q + 0], d0);
                d1 = fmaf(rlane(a, 4 * q + 1), Ecol[4 * q + 1], d1);
                d2 = fmaf(rlane(a, 4 * q + 2), Ecol[4 * q + 2], d2);
                d3 = fmaf(rlane(a, 4 * q + 3), Ecol[4 * q + 3], d3);
            }
            float cand = ((d0 + d1) + (d2 + d3)) * fb[s];
            bool keep = (kb >> s) & 1ULL;
            bool first = (c == 0) && (s == 0);
            a = first ? (esjj * fb[0]) : (keep ? cand : a);
        }
        // exact power-of-2 rescale (avoids overflow; ~10^24 worst per chunk)
        float m = a;
#pragma unroll
        for (int o = 32; o; o >>= 1) m = fmaxf(m, __shfl_xor(m, o));
        int ex;
        (void)frexpf(m, &ex);
        a *= ldexpf(1.0f, -ex);
        excorr += ex;
#pragma unroll
        for (int k = 0; k < CH; ++k) eb[k] = en[k];
        mb = mn;
    }
    // denominator: log(sum_j a_j * exp(end_j)) + excorr*ln2
    float term = (lane < T) ? a * __expf(endv[lane]) : 0.f;
#pragma unroll
    for (int o = 32; o; o >>= 1) term += __shfl_xor(term, o);
    if (lane == 0) den[b] = __logf(term) + (float)excorr * 0.69314718056f;

    // numerator (raw logits; lse cancels in num-den)
    float part = 0.f; int Lc = 0;
    for (int t = lane; t < 512; t += 64) {
        int mt = mask[b * 512 + t];
        Lc += (mt > 0);
        if (t >= 1 && mt > 0) {
            int tg = targ[b * 512 + t];
            int pg = targ[b * 512 + t - 1];
            part += trans[pg * T + tg] + logits[((size_t)b * 512 + t) * T + tg];
        }
    }
#pragma unroll
    for (int o = 32; o; o >>= 1) { part += __shfl_xor(part, o); Lc += __shfl_xor(Lc, o); }
    if (lane == 0) {
        int t0g = targ[b * 512];
        num[b] = start[t0g] + logits[(size_t)b * 512 * T + t0g]
               + part + endv[targ[b * 512 + Lc - 1]];
    }
}

// Viterbi forward, max only; stores score vectors for later argmax recompute.
// Same readlane broadcast; max is order-exact so scores are bitwise
// unchanged vs the LDS version (hist recompute stays bit-identical).
template <int T, int PAD>
__device__ void vit_fwd(int b,
    const float* __restrict__ logits, const int* __restrict__ mask,
    const float* __restrict__ start, const float* __restrict__ trans,
    float* __restrict__ score)
{
    const int lane = threadIdx.x;
    const int jj = (lane < T) ? lane : (T - 1);
    float Tcol[PAD];
#pragma unroll
    for (int i = 0; i < PAD; ++i) Tcol[i] = (i < T) ? trans[i * T + jj] : -1e30f;
    const float sjj = start[jj];
    const float* eptr = logits + (size_t)b * 512 * T + jj;
    const int* mptr = mask + b * 512;
    float* sptr = score + (size_t)b * 512 * T + lane;

    float eb[CH], en[CH];
    int mb, mn = 0;
#pragma unroll
    for (int k = 0; k < CH; ++k) { eb[k] = eptr[k * T]; en[k] = 0.f; }
    mb = mptr[lane & (CH - 1)];

    float sc = 0.f;
    for (int c = 0; c < 64; ++c) {
        unsigned long long kb = __ballot(mb > 0);
        if (c < 63) {
            const float* ep2 = eptr + (c + 1) * CH * T;
#pragma unroll
            for (int k = 0; k < CH; ++k) en[k] = ep2[k * T];
            mn = mptr[(c + 1) * CH + (lane & (CH - 1))];
        }
#pragma unroll
        for (int s = 0; s < CH; ++s) {
            float m = -1e30f;
#pragma unroll
            for (int q = 0; q < PAD / 4; ++q) {
                float ca = rlane(sc, 4 * q + 0) + Tcol[4 * q + 0];
                float cb = rlane(sc, 4 * q + 1) + Tcol[4 * q + 1];
                float cc = rlane(sc, 4 * q + 2) + Tcol[4 * q + 2];
                float cd = rlane(sc, 4 * q + 3) + Tcol[4 * q + 3];
                m = fmaxf(m, fmaxf(ca, cb));   // -> v_max3
                m = fmaxf(m, fmaxf(cc, cd));
            }
            float nxt = m + eb[s];
            bool keep = (kb >> s) & 1ULL;
            bool first = (c == 0) && (s == 0);
            sc = first ? (sjj + eb[0]) : (keep ? nxt : sc);
            if (lane < T) sptr[(size_t)(c * CH + s) * T] = sc;
        }
#pragma unroll
        for (int k = 0; k < CH; ++k) eb[k] = en[k];
        mb = mn;
    }
}

__global__ __launch_bounds__(64, 1) void scan_kernel(
    const float* tagL, const float* posL, const int* mask,
    const int* tgT, const int* tgP,
    const float* startT, const float* transT, const float* endT,
    const float* startP, const float* transP, const float* endP,
    float* scoreT, float* scoreP,
    float* denT, float* denP, float* numT, float* numP)
{
    int bid = blockIdx.x;
    if (bid < 64)
        vit_fwd<NP, 48>(bid, posL, mask, startP, transP, scoreP);
    else if (bid < 128)
        nll_scan<NP, 48>(bid - 64, posL, mask, tgP, startP, transP, endP, denP, numP);
    else if (bid < 192)
        vit_fwd<NT, 20>(bid - 128, tagL, mask, startT, transT, scoreT);
    else
        nll_scan<NT, 20>(bid - 192, tagL, mask, tgT, startT, transT, endT, denT, numT);
}

// ---------------------------------------------------------------------------
// Kernel 3: recompute Viterbi backpointers massively parallel over (b,t).
// Bit-identical adds vs forward pass => identical argmax.
// ---------------------------------------------------------------------------
template <int T>
__device__ void hist_block(int b, int tc,
    const float* __restrict__ score, const int* __restrict__ mask,
    const float* __restrict__ trans, unsigned char* __restrict__ hist)
{
    const int wave = threadIdx.x >> 6;
    const int lane = threadIdx.x & 63;
    const int jj = (lane < T) ? lane : (T - 1);
    float Tcol[T];
#pragma unroll
    for (int i = 0; i < T; ++i) Tcol[i] = trans[i * T + jj];
    for (int q = 0; q < 16; ++q) {
        int t = tc * 64 + wave * 16 + q;
        if (t < 1) continue;
        int mt = mask[b * 512 + t];
        int hv;
        if (mt > 0) {
            float sv = score[((size_t)b * 512 + t - 1) * T + jj];
            float mx = -1e30f; int am = 0;
#pragma unroll
            for (int i = 0; i < T; ++i) {
                float cand = rlane(sv, i) + Tcol[i];
                bool g = cand > mx;            // strict > keeps FIRST max
                mx = g ? cand : mx;
                am = g ? i : am;
            }
            hv = am;
        } else {
            hv = jj;                           // identity when masked
        }
        if (lane < T)
            hist[((size_t)b * 512 + (t - 1)) * T + lane] = (unsigned char)hv;
    }
}

__global__ __launch_bounds__(256) void hist_kernel(
    const float* scoreT, const float* scoreP, const int* mask,
    const float* transT, const float* transP,
    unsigned char* histT, unsigned char* histP)
{
    int blk = blockIdx.x;
    if (blk < 512) hist_block<NP>(blk >> 3, blk & 7, scoreP, mask, transP, histP);
    else { blk -= 512; hist_block<NT>(blk >> 3, blk & 7, scoreT, mask, transT, histT); }
}

// ---------------------------------------------------------------------------
// Kernel 4: backtrace with pointer-jump composition (serial chain 511 -> 63).
// ---------------------------------------------------------------------------
template <int T>
__device__ void backtrace(int b, const float* __restrict__ score,
    const unsigned char* __restrict__ hist, const float* __restrict__ endv,
    float* __restrict__ outp, unsigned char* sh)
{
    unsigned char* h  = sh;                    // 512*T
    unsigned char* g2 = sh + 512 * T;          // rows 0..509
    unsigned char* g4 = sh + 1024 * T;         // 127 rows (r = 3+4*a4)
    unsigned char* g8 = sh + 1024 * T + 128 * T; // 63 rows (r = 503-8a)
    unsigned char* pr = sh + 1024 * T + 192 * T; // 512
    const int lane = threadIdx.x;

    {   // stage hist to LDS (b-stride = 512*T bytes, 16B multiple)
        const int4* src = (const int4*)(hist + (size_t)b * 512 * T);
        int4* dst = (int4*)h;
        int n16 = (512 * T) / 16;
        for (int i = lane; i < n16; i += 64) dst[i] = src[i];
    }
    __syncthreads();
    // g2[r][i] = h[r][h[r+1][i]]  (maps cur at t=r+2 -> t=r)
    for (int idx = lane; idx < 510 * T; idx += 64) {
        int r = idx / T, i = idx - r * T;
        g2[idx] = h[r * T + h[(r + 1) * T + i]];
    }
    __syncthreads();
    // g4 rows r = 3+4*a4: g4[a4][i] = g2[r][ g2[r+2][i] ]  (t=r+4 -> r)
    for (int idx = lane; idx < 127 * T; idx += 64) {
        int a4 = idx / T, i = idx - a4 * T;
        int r = 3 + 4 * a4;
        g4[idx] = g2[r * T + g2[(r + 2) * T + i]];
    }
    __syncthreads();
    // g8 rows r = 503-8a: g8[a][i] = g4row(r)[ g4row(r+4)[i] ]  (t=r+8 -> r)
    for (int idx = lane; idx < 63 * T; idx += 64) {
        int a = idx / T, i = idx - a * T;
        int r = 503 - 8 * a;
        int a4lo = (r - 3) >> 2, a4hi = (r + 1) >> 2;
        g8[idx] = g4[a4lo * T + g4[a4hi * T + i]];
    }
    // last = first-index argmax(score[511] + end)
    float v = (lane < T) ? (score[((size_t)b * 512 + 511) * T + lane] + endv[lane]) : -1e30f;
    float mx = v;
#pragma unroll
    for (int o = 32; o; o >>= 1) mx = fmaxf(mx, __shfl_xor(mx, o));
    unsigned long long bal = __ballot(v == mx);
    int cur = __ffsll(bal) - 1;
    __syncthreads();
    // phase A: serial anchor chain, 63 dependent LDS reads
    int myCur = 0;
    for (int a = 0; a < 64; ++a) {
        if (lane == a) myCur = cur;
        if (a < 63) cur = g8[a * T + cur];
    }
    // phase B: each lane fills its 8-step segment
    {
        int ta = 511 - 8 * lane;
        int j = myCur;
        pr[ta] = (unsigned char)j;
        int rlo = (lane == 63) ? 0 : (ta - 7);
        for (int r = ta - 1; r >= rlo; --r) {
            j = h[r * T + j];
            pr[r] = (unsigned char)j;
        }
    }
    __syncthreads();
    for (int k = lane; k < 512; k += 64)
        outp[(size_t)b * 512 + k] = (float)pr[k];
}

__global__ __launch_bounds__(64, 1) void backtrace_kernel(
    const float* scoreT, const float* scoreP,
    const unsigned char* histT, const unsigned char* histP,
    const float* endT, const float* endP, float* out)
{
    __shared__ __align__(16) unsigned char sh[1216 * NP + 576];
    int blk = blockIdx.x;
    if (blk < 64) backtrace<NP>(blk, scoreP, histP, endP, out + 32768, sh);
    else backtrace<NT>(blk - 64, scoreT, histT, endT, out, sh);
}

// ---------------------------------------------------------------------------
// Kernel 5: losses = -mean(num - den)
// ---------------------------------------------------------------------------
__global__ __launch_bounds__(64) void finalize_kernel(
    const float* numT, const float* denT, const float* numP, const float* denP,
    float* out)
{
    int lane = threadIdx.x;
    float dT = numT[lane] - denT[lane];
    float dP = numP[lane] - denP[lane];
#pragma unroll
    for (int o = 32; o; o >>= 1) { dT += __shfl_xor(dT, o); dP += __shfl_xor(dP, o); }
    if (lane == 0) {
        out[65536] = -dT / 64.f;
        out[65537] = -dP / 64.f;
    }
}

// ---------------------------------------------------------------------------
extern "C" void kernel_launch(void* const* d_in, const int* in_sizes, int n_in,
                              void* d_out, int out_size, void* d_ws, size_t ws_size,
                              hipStream_t stream)
{
    const float* hidden = (const float*)d_in[0];
    const int*   mask   = (const int*)d_in[1];
    const int*   tgT    = (const int*)d_in[2];
    const int*   tgP    = (const int*)d_in[3];
    const float* Wt     = (const float*)d_in[4];
    const float* bt     = (const float*)d_in[5];
    const float* Wp     = (const float*)d_in[6];
    const float* bp     = (const float*)d_in[7];
    const float* startT = (const float*)d_in[8];
    const float* transT = (const float*)d_in[9];
    const float* endT   = (const float*)d_in[10];
    const float* startP = (const float*)d_in[11];
    const float* transP = (const float*)d_in[12];
    const float* endP   = (const float*)d_in[13];

    float* ws     = (float*)d_ws;
    float* tagL   = ws;                         // 557056
    float* posL   = tagL + 557056;              // 1474560
    float* scoreT = posL + 1474560;             // 557056
    float* scoreP = scoreT + 557056;            // 1474560
    float* denT   = scoreP + 1474560;           // 64
    float* denP   = denT + 64;
    float* numT   = denP + 64;
    float* numP   = numT + 64;
    unsigned char* histT = (unsigned char*)(numP + 64);       // 64*512*17 B
    unsigned char* histP = histT + (size_t)64 * 512 * NT;     // 64*512*45 B
    float* out = (float*)d_out;

    gemm_logits<<<1024, 256, 0, stream>>>(hidden, Wt, bt, Wp, bp, tagL, posL);
    scan_kernel<<<256, 64, 0, stream>>>(tagL, posL, mask, tgT, tgP,
        startT, transT, endT, startP, transP, endP,
        scoreT, scoreP, denT, denP, numT, numP);
    hist_kernel<<<1024, 256, 0, stream>>>(scoreT, scoreP, mask, transT, transP,
        histT, histP);
    backtrace_kernel<<<128, 64, 0, stream>>>(scoreT, scoreP, histT, histP,
        endT, endP, out);
    finalize_kernel<<<1, 64, 0, stream>>>(numT, denT, numP, denP, out);
}

// Round 4
// 516.836 us; speedup vs baseline: 1.2476x; 1.2476x over previous
//
#include <hip/hip_runtime.h>
#include <cmath>
#include <cstdint>
#include <cstddef>

#define NT 17
#define NP 45
#define CH 8
// B=64, S=512, H=768

__device__ __forceinline__ float rlane(float v, int k) {
    return __int_as_float(__builtin_amdgcn_readlane(__float_as_int(v), k));
}

// ---------------------------------------------------------------------------
// Kernel 1: logits = hidden @ [W_tag | W_pos] + bias   (f32 vector GEMM)
//
// Col-mapped, LDS-free, barrier-free: lane = output column (62 real, 64
// padded); each wave owns 8 rows x full K. Lessons: s_load can't pipeline
// (lgkmcnt is one unordered counter -- any consume drains the prefetch,
// round 2), and uniform-address VMEM costs a full instruction + L1 txn per
// 16B (round 3). Fix: lane-indexed hidden delivery -- lane carries k within
// a 64-wide chunk, so ONE coalesced dword load per row covers 64 k-steps;
// the FMA consumes rlane(h_r, kk) with compile-time kk (VALU broadcast, the
// same trick that fixed the scans). W[k][c] is a per-lane coalesced load
// (248B rows, L1-hot), prefetched one 8-k sub-chunk ahead on the counted
// vmcnt pipe. Accumulation is a single fmaf chain in strictly ascending k
// with bias added last -- bitwise identical to all previous versions, so
// downstream argmax/losses are unchanged.
// ---------------------------------------------------------------------------
__global__ __launch_bounds__(256) void gemm_logits(
    const float* __restrict__ hidden, const float* __restrict__ Wt,
    const float* __restrict__ bt, const float* __restrict__ Wp,
    const float* __restrict__ bp, float* __restrict__ tagL,
    float* __restrict__ posL)
{
    const int lane = threadIdx.x & 63;
    const int wid  = threadIdx.x >> 6;
    const int c = (lane < 62) ? lane : 61;          // clamp pad lanes
    const bool isTag = (c < NT);
    const float* wbase = isTag ? (Wt + c) : (Wp + (c - NT));
    const int wstride = isTag ? NT : NP;
    const float bias = isTag ? bt[c] : bp[c - NT];

    const int row0 = blockIdx.x * 32 + wid * 8;
    const float* h0 = hidden + (size_t)row0 * 768 + lane;   // lane = k offset

    float acc[8];
#pragma unroll
    for (int r = 0; r < 8; ++r) acc[r] = 0.f;

    float hcur[8], hnext[8];
#pragma unroll
    for (int r = 0; r < 8; ++r) hcur[r] = h0[r * 768];      // k-chunk 0

    float wv[8], wn[8];
#pragma unroll
    for (int j = 0; j < 8; ++j) wv[j] = wbase[(size_t)j * wstride];  // k=0..7

#pragma unroll 1
    for (int kc = 0; kc < 768; kc += 64) {
        // prefetch next chunk's hidden (8 coalesced dword loads, consumed
        // one full chunk later -> latency fully hidden under 1024 VALU ops)
        if (kc + 64 < 768) {
#pragma unroll
            for (int r = 0; r < 8; ++r)
                hnext[r] = h0[r * 768 + kc + 64];
        }
#pragma unroll
        for (int k8 = 0; k8 < 8; ++k8) {
            // prefetch next 8 W values (per-lane coalesced, L1-hot)
            const int knext = kc + (k8 + 1) * 8;
            if (knext < 768) {
#pragma unroll
                for (int j = 0; j < 8; ++j)
                    wn[j] = wbase[(size_t)(knext + j) * wstride];
            }
#pragma unroll
            for (int j = 0; j < 8; ++j) {
                // kk is compile-time (k8, j both unrolled) -> readlane imm
#pragma unroll
                for (int r = 0; r < 8; ++r)
                    acc[r] = fmaf(rlane(hcur[r], k8 * 8 + j), wv[j], acc[r]);
            }
#pragma unroll
            for (int j = 0; j < 8; ++j) wv[j] = wn[j];
        }
#pragma unroll
        for (int r = 0; r < 8; ++r) hcur[r] = hnext[r];
    }

    if (lane < 62) {
#pragma unroll
        for (int r = 0; r < 8; ++r) {
            float v = acc[r] + bias;
            size_t row = (size_t)row0 + r;
            if (isTag) tagL[row * NT + c] = v;
            else       posL[row * NP + (c - NT)] = v;
        }
    }
}

// ---------------------------------------------------------------------------
// Kernel 2: the four CRF scans. One wave per (b, role); 256 blocks x 64 thr.
// All-to-all broadcast of the state vector via v_readlane (compile-time lane
// indices); accumulation order kept EXACTLY as the original LDS version so
// results are bitwise unchanged. NLL runs in LINEAR space (f = exp(e)
// precomputed off-chain per chunk; exact power-of-2 rescale per chunk).
// ---------------------------------------------------------------------------
template <int T, int PAD>
__device__ void nll_scan(int b,
    const float* __restrict__ logits, const int* __restrict__ mask,
    const int* __restrict__ targ, const float* __restrict__ start,
    const float* __restrict__ trans, const float* __restrict__ endv,
    float* __restrict__ den, float* __restrict__ num)
{
    const int lane = threadIdx.x;
    const int jj = (lane < T) ? lane : (T - 1);
    float Ecol[PAD];
#pragma unroll
    for (int i = 0; i < PAD; ++i) Ecol[i] = (i < T) ? __expf(trans[i * T + jj]) : 0.f;
    const float esjj = __expf(start[jj]);
    const float* eptr = logits + (size_t)b * 512 * T + jj;
    const int* mptr = mask + b * 512;

    float eb[CH], en[CH], fb[CH];
    int mb, mn = 0;
#pragma unroll
    for (int k = 0; k < CH; ++k) { eb[k] = eptr[k * T]; en[k] = 0.f; }
    mb = mptr[lane & (CH - 1)];

    float a = 0.f;
    int excorr = 0;
    for (int c = 0; c < 64; ++c) {
        unsigned long long kb = __ballot(mb > 0);
        if (c < 63) {
            const float* ep2 = eptr + (c + 1) * CH * T;
#pragma unroll
            for (int k = 0; k < CH; ++k) en[k] = ep2[k * T];
            mn = mptr[(c + 1) * CH + (lane & (CH - 1))];
        }
#pragma unroll
        for (int k = 0; k < CH; ++k) fb[k] = __expf(eb[k]);   // off-chain
#pragma unroll
        for (int s = 0; s < CH; ++s) {
            // readlane broadcast of a; lanes >= T hold a duplicate of column
            // T-1 and Ecol there is 0, so fma contributes exactly 0.
            float d0 = 0.f, d1 = 0.f, d2 = 0.f, d3 = 0.f;
#pragma unroll
            for (int q = 0; q < PAD / 4; ++q) {
                d0 = fmaf(rlane(a, 4 * q + 0), Ecol[4 * q + 0], d0);
                d1 = fmaf(rlane(a, 4 * q + 1), Ecol[4 * q + 1], d1);
                d2 = fmaf(rlane(a, 4 * q + 2), Ecol[4 * q + 2], d2);
                d3 = fmaf(rlane(a, 4 * q + 3), Ecol[4 * q + 3], d3);
            }
            float cand = ((d0 + d1) + (d2 + d3)) * fb[s];
            bool keep = (kb >> s) & 1ULL;
            bool first = (c == 0) && (s == 0);
            a = first ? (esjj * fb[0]) : (keep ? cand : a);
        }
        // exact power-of-2 rescale (avoids overflow; ~10^24 worst per chunk)
        float m = a;
#pragma unroll
        for (int o = 32; o; o >>= 1) m = fmaxf(m, __shfl_xor(m, o));
        int ex;
        (void)frexpf(m, &ex);
        a *= ldexpf(1.0f, -ex);
        excorr += ex;
#pragma unroll
        for (int k = 0; k < CH; ++k) eb[k] = en[k];
        mb = mn;
    }
    // denominator: log(sum_j a_j * exp(end_j)) + excorr*ln2
    float term = (lane < T) ? a * __expf(endv[lane]) : 0.f;
#pragma unroll
    for (int o = 32; o; o >>= 1) term += __shfl_xor(term, o);
    if (lane == 0) den[b] = __logf(term) + (float)excorr * 0.69314718056f;

    // numerator (raw logits; lse cancels in num-den)
    float part = 0.f; int Lc = 0;
    for (int t = lane; t < 512; t += 64) {
        int mt = mask[b * 512 + t];
        Lc += (mt > 0);
        if (t >= 1 && mt > 0) {
            int tg = targ[b * 512 + t];
            int pg = targ[b * 512 + t - 1];
            part += trans[pg * T + tg] + logits[((size_t)b * 512 + t) * T + tg];
        }
    }
#pragma unroll
    for (int o = 32; o; o >>= 1) { part += __shfl_xor(part, o); Lc += __shfl_xor(Lc, o); }
    if (lane == 0) {
        int t0g = targ[b * 512];
        num[b] = start[t0g] + logits[(size_t)b * 512 * T + t0g]
               + part + endv[targ[b * 512 + Lc - 1]];
    }
}

// Viterbi forward, max only; stores score vectors for later argmax recompute.
// Same readlane broadcast; max is order-exact so scores are bitwise
// unchanged vs the LDS version (hist recompute stays bit-identical).
template <int T, int PAD>
__device__ void vit_fwd(int b,
    const float* __restrict__ logits, const int* __restrict__ mask,
    const float* __restrict__ start, const float* __restrict__ trans,
    float* __restrict__ score)
{
    const int lane = threadIdx.x;
    const int jj = (lane < T) ? lane : (T - 1);
    float Tcol[PAD];
#pragma unroll
    for (int i = 0; i < PAD; ++i) Tcol[i] = (i < T) ? trans[i * T + jj] : -1e30f;
    const float sjj = start[jj];
    const float* eptr = logits + (size_t)b * 512 * T + jj;
    const int* mptr = mask + b * 512;
    float* sptr = score + (size_t)b * 512 * T + lane;

    float eb[CH], en[CH];
    int mb, mn = 0;
#pragma unroll
    for (int k = 0; k < CH; ++k) { eb[k] = eptr[k * T]; en[k] = 0.f; }
    mb = mptr[lane & (CH - 1)];

    float sc = 0.f;
    for (int c = 0; c < 64; ++c) {
        unsigned long long kb = __ballot(mb > 0);
        if (c < 63) {
            const float* ep2 = eptr + (c + 1) * CH * T;
#pragma unroll
            for (int k = 0; k < CH; ++k) en[k] = ep2[k * T];
            mn = mptr[(c + 1) * CH + (lane & (CH - 1))];
        }
#pragma unroll
        for (int s = 0; s < CH; ++s) {
            float m = -1e30f;
#pragma unroll
            for (int q = 0; q < PAD / 4; ++q) {
                float ca = rlane(sc, 4 * q + 0) + Tcol[4 * q + 0];
                float cb = rlane(sc, 4 * q + 1) + Tcol[4 * q + 1];
                float cc = rlane(sc, 4 * q + 2) + Tcol[4 * q + 2];
                float cd = rlane(sc, 4 * q + 3) + Tcol[4 * q + 3];
                m = fmaxf(m, fmaxf(ca, cb));   // -> v_max3
                m = fmaxf(m, fmaxf(cc, cd));
            }
            float nxt = m + eb[s];
            bool keep = (kb >> s) & 1ULL;
            bool first = (c == 0) && (s == 0);
            sc = first ? (sjj + eb[0]) : (keep ? nxt : sc);
            if (lane < T) sptr[(size_t)(c * CH + s) * T] = sc;
        }
#pragma unroll
        for (int k = 0; k < CH; ++k) eb[k] = en[k];
        mb = mn;
    }
}

__global__ __launch_bounds__(64, 1) void scan_kernel(
    const float* tagL, const float* posL, const int* mask,
    const int* tgT, const int* tgP,
    const float* startT, const float* transT, const float* endT,
    const float* startP, const float* transP, const float* endP,
    float* scoreT, float* scoreP,
    float* denT, float* denP, float* numT, float* numP)
{
    int bid = blockIdx.x;
    if (bid < 64)
        vit_fwd<NP, 48>(bid, posL, mask, startP, transP, scoreP);
    else if (bid < 128)
        nll_scan<NP, 48>(bid - 64, posL, mask, tgP, startP, transP, endP, denP, numP);
    else if (bid < 192)
        vit_fwd<NT, 20>(bid - 128, tagL, mask, startT, transT, scoreT);
    else
        nll_scan<NT, 20>(bid - 192, tagL, mask, tgT, startT, transT, endT, denT, numT);
}

// ---------------------------------------------------------------------------
// Kernel 3: recompute Viterbi backpointers massively parallel over (b,t).
// Bit-identical adds vs forward pass => identical argmax.
// ---------------------------------------------------------------------------
template <int T>
__device__ void hist_block(int b, int tc,
    const float* __restrict__ score, const int* __restrict__ mask,
    const float* __restrict__ trans, unsigned char* __restrict__ hist)
{
    const int wave = threadIdx.x >> 6;
    const int lane = threadIdx.x & 63;
    const int jj = (lane < T) ? lane : (T - 1);
    float Tcol[T];
#pragma unroll
    for (int i = 0; i < T; ++i) Tcol[i] = trans[i * T + jj];
    for (int q = 0; q < 16; ++q) {
        int t = tc * 64 + wave * 16 + q;
        if (t < 1) continue;
        int mt = mask[b * 512 + t];
        int hv;
        if (mt > 0) {
            float sv = score[((size_t)b * 512 + t - 1) * T + jj];
            float mx = -1e30f; int am = 0;
#pragma unroll
            for (int i = 0; i < T; ++i) {
                float cand = rlane(sv, i) + Tcol[i];
                bool g = cand > mx;            // strict > keeps FIRST max
                mx = g ? cand : mx;
                am = g ? i : am;
            }
            hv = am;
        } else {
            hv = jj;                           // identity when masked
        }
        if (lane < T)
            hist[((size_t)b * 512 + (t - 1)) * T + lane] = (unsigned char)hv;
    }
}

__global__ __launch_bounds__(256) void hist_kernel(
    const float* scoreT, const float* scoreP, const int* mask,
    const float* transT, const float* transP,
    unsigned char* histT, unsigned char* histP)
{
    int blk = blockIdx.x;
    if (blk < 512) hist_block<NP>(blk >> 3, blk & 7, scoreP, mask, transP, histP);
    else { blk -= 512; hist_block<NT>(blk >> 3, blk & 7, scoreT, mask, transT, histT); }
}

// ---------------------------------------------------------------------------
// Kernel 4: backtrace with pointer-jump composition (serial chain 511 -> 63).
// ---------------------------------------------------------------------------
template <int T>
__device__ void backtrace(int b, const float* __restrict__ score,
    const unsigned char* __restrict__ hist, const float* __restrict__ endv,
    float* __restrict__ outp, unsigned char* sh)
{
    unsigned char* h  = sh;                    // 512*T
    unsigned char* g2 = sh + 512 * T;          // rows 0..509
    unsigned char* g4 = sh + 1024 * T;         // 127 rows (r = 3+4*a4)
    unsigned char* g8 = sh + 1024 * T + 128 * T; // 63 rows (r = 503-8a)
    unsigned char* pr = sh + 1024 * T + 192 * T; // 512
    const int lane = threadIdx.x;

    {   // stage hist to LDS (b-stride = 512*T bytes, 16B multiple)
        const int4* src = (const int4*)(hist + (size_t)b * 512 * T);
        int4* dst = (int4*)h;
        int n16 = (512 * T) / 16;
        for (int i = lane; i < n16; i += 64) dst[i] = src[i];
    }
    __syncthreads();
    // g2[r][i] = h[r][h[r+1][i]]  (maps cur at t=r+2 -> t=r)
    for (int idx = lane; idx < 510 * T; idx += 64) {
        int r = idx / T, i = idx - r * T;
        g2[idx] = h[r * T + h[(r + 1) * T + i]];
    }
    __syncthreads();
    // g4 rows r = 3+4*a4: g4[a4][i] = g2[r][ g2[r+2][i] ]  (t=r+4 -> r)
    for (int idx = lane; idx < 127 * T; idx += 64) {
        int a4 = idx / T, i = idx - a4 * T;
        int r = 3 + 4 * a4;
        g4[idx] = g2[r * T + g2[(r + 2) * T + i]];
    }
    __syncthreads();
    // g8 rows r = 503-8a: g8[a][i] = g4row(r)[ g4row(r+4)[i] ]  (t=r+8 -> r)
    for (int idx = lane; idx < 63 * T; idx += 64) {
        int a = idx / T, i = idx - a * T;
        int r = 503 - 8 * a;
        int a4lo = (r - 3) >> 2, a4hi = (r + 1) >> 2;
        g8[idx] = g4[a4lo * T + g4[a4hi * T + i]];
    }
    // last = first-index argmax(score[511] + end)
    float v = (lane < T) ? (score[((size_t)b * 512 + 511) * T + lane] + endv[lane]) : -1e30f;
    float mx = v;
#pragma unroll
    for (int o = 32; o; o >>= 1) mx = fmaxf(mx, __shfl_xor(mx, o));
    unsigned long long bal = __ballot(v == mx);
    int cur = __ffsll(bal) - 1;
    __syncthreads();
    // phase A: serial anchor chain, 63 dependent LDS reads
    int myCur = 0;
    for (int a = 0; a < 64; ++a) {
        if (lane == a) myCur = cur;
        if (a < 63) cur = g8[a * T + cur];
    }
    // phase B: each lane fills its 8-step segment
    {
        int ta = 511 - 8 * lane;
        int j = myCur;
        pr[ta] = (unsigned char)j;
        int rlo = (lane == 63) ? 0 : (ta - 7);
        for (int r = ta - 1; r >= rlo; --r) {
            j = h[r * T + j];
            pr[r] = (unsigned char)j;
        }
    }
    __syncthreads();
    for (int k = lane; k < 512; k += 64)
        outp[(size_t)b * 512 + k] = (float)pr[k];
}

__global__ __launch_bounds__(64, 1) void backtrace_kernel(
    const float* scoreT, const float* scoreP,
    const unsigned char* histT, const unsigned char* histP,
    const float* endT, const float* endP, float* out)
{
    __shared__ __align__(16) unsigned char sh[1216 * NP + 576];
    int blk = blockIdx.x;
    if (blk < 64) backtrace<NP>(blk, scoreP, histP, endP, out + 32768, sh);
    else backtrace<NT>(blk - 64, scoreT, histT, endT, out, sh);
}

// ---------------------------------------------------------------------------
// Kernel 5: losses = -mean(num - den)
// ---------------------------------------------------------------------------
__global__ __launch_bounds__(64) void finalize_kernel(
    const float* numT, const float* denT, const float* numP, const float* denP,
    float* out)
{
    int lane = threadIdx.x;
    float dT = numT[lane] - denT[lane];
    float dP = numP[lane] - denP[lane];
#pragma unroll
    for (int o = 32; o; o >>= 1) { dT += __shfl_xor(dT, o); dP += __shfl_xor(dP, o); }
    if (lane == 0) {
        out[65536] = -dT / 64.f;
        out[65537] = -dP / 64.f;
    }
}

// ---------------------------------------------------------------------------
extern "C" void kernel_launch(void* const* d_in, const int* in_sizes, int n_in,
                              void* d_out, int out_size, void* d_ws, size_t ws_size,
                              hipStream_t stream)
{
    const float* hidden = (const float*)d_in[0];
    const int*   mask   = (const int*)d_in[1];
    const int*   tgT    = (const int*)d_in[2];
    const int*   tgP    = (const int*)d_in[3];
    const float* Wt     = (const float*)d_in[4];
    const float* bt     = (const float*)d_in[5];
    const float* Wp     = (const float*)d_in[6];
    const float* bp     = (const float*)d_in[7];
    const float* startT = (const float*)d_in[8];
    const float* transT = (const float*)d_in[9];
    const float* endT   = (const float*)d_in[10];
    const float* startP = (const float*)d_in[11];
    const float* transP = (const float*)d_in[12];
    const float* endP   = (const float*)d_in[13];

    float* ws     = (float*)d_ws;
    float* tagL   = ws;                         // 557056
    float* posL   = tagL + 557056;              // 1474560
    float* scoreT = posL + 1474560;             // 557056
    float* scoreP = scoreT + 557056;            // 1474560
    float* denT   = scoreP + 1474560;           // 64
    float* denP   = denT + 64;
    float* numT   = denP + 64;
    float* numP   = numT + 64;
    unsigned char* histT = (unsigned char*)(numP + 64);       // 64*512*17 B
    unsigned char* histP = histT + (size_t)64 * 512 * NT;     // 64*512*45 B
    float* out = (float*)d_out;

    gemm_logits<<<1024, 256, 0, stream>>>(hidden, Wt, bt, Wp, bp, tagL, posL);
    scan_kernel<<<256, 64, 0, stream>>>(tagL, posL, mask, tgT, tgP,
        startT, transT, endT, startP, transP, endP,
        scoreT, scoreP, denT, denP, numT, numP);
    hist_kernel<<<1024, 256, 0, stream>>>(scoreT, scoreP, mask, transT, transP,
        histT, histP);
    backtrace_kernel<<<128, 64, 0, stream>>>(scoreT, scoreP, histT, histP,
        endT, endP, out);
    finalize_kernel<<<1, 64, 0, stream>>>(numT, denT, numP, denP, out);
}

// Round 5
// 412.396 us; speedup vs baseline: 1.5635x; 1.2533x over previous
//
#include <hip/hip_runtime.h>
#include <cmath>
#include <cstdint>
#include <cstddef>

#define NT 17
#define NP 45
#define CH 8
// B=64, S=512, H=768

__device__ __forceinline__ float rlane(float v, int k) {
    return __int_as_float(__builtin_amdgcn_readlane(__float_as_int(v), k));
}

// 16B async global->LDS DMA (no VGPR round-trip, no ds_write instruction).
__device__ __forceinline__ void gload16(const float* g, float* l) {
    __builtin_amdgcn_global_load_lds(
        (const __attribute__((address_space(1))) void*)g,
        (__attribute__((address_space(3))) void*)l, 16, 0, 0);
}

// ---------------------------------------------------------------------------
// Kernel 0: pack W into Wpk[768][64] (17 tag cols | 45 pos cols | 2 zero pad)
// so Bs staging has contiguous 16B-aligned source rows for global_load_lds.
// ---------------------------------------------------------------------------
__global__ __launch_bounds__(256) void pack_w(
    const float* __restrict__ Wt, const float* __restrict__ Wp,
    float* __restrict__ Wpk)
{
    int i = blockIdx.x * 256 + threadIdx.x;
    if (i >= 768 * 64) return;
    int k = i >> 6, c = i & 63;
    float v = 0.f;
    if (c < NT) v = Wt[k * NT + c];
    else if (c < NT + NP) v = Wp[k * NP + (c - NT)];
    Wpk[i] = v;
}

// ---------------------------------------------------------------------------
// Kernel 1: logits = hidden @ [W_tag | W_pos] + bias   (f32 vector GEMM)
//
// Round-1 tiled structure (64 rows x 62 cols, K-chunks of 32, 4x4 per
// thread) but with ALL staging via global_load_lds DMA:
//  - Bs [32][64] from Wpk: linear dest, contiguous source. Reads (b128 at
//    cg*16B) spread all banks 2-way -> conflict-free.
//  - As [64][32] row-major (DMA-linear dest) with SOURCE-side XOR swizzle
//    (rule: swizzle both sides or neither): LDS slot q of row r holds
//    k-group (q ^ ((r>>2)&7)); reads use the same XOR -> the 16 rg-groups
//    spread across all 32 banks, 2-way (free). No As transpose, so the old
//    4-way-conflicted ds_writes (2.36M conflict cycles) are gone entirely.
// Zero LDS instructions for staging, ~64 broadcast-heavy ds_read_b128 per
// thread per chunk, m97-style 2-barrier sync.
// Accumulation per output is the identical strictly-ascending-k fmaf chain
// (k4 outer, kk inner == k = kc..kc+31 in order) with bias added last ->
// logits bitwise unchanged vs all previous rounds.
// ---------------------------------------------------------------------------
__global__ __launch_bounds__(256) void gemm_logits(
    const float* __restrict__ hidden, const float* __restrict__ Wpk,
    const float* __restrict__ bt, const float* __restrict__ bp,
    float* __restrict__ tagL, float* __restrict__ posL)
{
    __shared__ __align__(16) float As[64 * 32];
    __shared__ __align__(16) float Bs[32 * 64];
    const int tid = threadIdx.x;
    const int rg = tid >> 4;          // 0..15 (row group)
    const int cg = tid & 15;          // 0..15 (col group)
    const int srg = rg & 7;
    const int row0 = blockIdx.x * 64;

    float acc[4][4];
#pragma unroll
    for (int a = 0; a < 4; ++a)
#pragma unroll
        for (int b = 0; b < 4; ++b) acc[a][b] = 0.f;

    // staging indices (all dest offsets are tid*16B -> DMA-linear per wave)
    const int arow = tid >> 3;        // 0..31
    const int aq   = tid & 7;         // 0..7  (k-group slot)
    const int bk   = tid >> 4;        // 0..15
    const int bc4  = tid & 15;        // 0..15

#pragma unroll 1
    for (int kc = 0; kc < 768; kc += 32) {
        {   // As rows 0..31 and 32..63: source k-group = slot ^ ((row>>2)&7)
            int r0 = arow;
            int s0 = (r0 >> 2) & 7;
            gload16(hidden + (size_t)(row0 + r0) * 768 + kc + ((aq ^ s0) << 2),
                    As + r0 * 32 + aq * 4);
            int r1 = 32 + arow;
            int s1 = (r1 >> 2) & 7;
            gload16(hidden + (size_t)(row0 + r1) * 768 + kc + ((aq ^ s1) << 2),
                    As + r1 * 32 + aq * 4);
            // Bs rows kc..kc+31 from packed W
            gload16(Wpk + (size_t)(kc + bk) * 64 + bc4 * 4,
                    Bs + bk * 64 + bc4 * 4);
            gload16(Wpk + (size_t)(kc + 16 + bk) * 64 + bc4 * 4,
                    Bs + (16 + bk) * 64 + bc4 * 4);
        }
        __syncthreads();              // implicit vmcnt(0): DMA landed
#pragma unroll
        for (int k4 = 0; k4 < 8; ++k4) {
            const int qb = ((k4 ^ srg) << 2);   // swizzled As slot offset
            float a_[4][4], b_[4][4];
#pragma unroll
            for (int jr = 0; jr < 4; ++jr) {
                float4 t = *(const float4*)(As + (rg * 4 + jr) * 32 + qb);
                a_[jr][0] = t.x; a_[jr][1] = t.y; a_[jr][2] = t.z; a_[jr][3] = t.w;
            }
#pragma unroll
            for (int kk = 0; kk < 4; ++kk) {
                float4 t = *(const float4*)(Bs + (k4 * 4 + kk) * 64 + cg * 4);
                b_[kk][0] = t.x; b_[kk][1] = t.y; b_[kk][2] = t.z; b_[kk][3] = t.w;
            }
#pragma unroll
            for (int kk = 0; kk < 4; ++kk)      // k strictly ascending
#pragma unroll
                for (int jr = 0; jr < 4; ++jr)
#pragma unroll
                    for (int jc = 0; jc < 4; ++jc)
                        acc[jr][jc] = fmaf(a_[jr][kk], b_[kk][jc], acc[jr][jc]);
        }
        __syncthreads();              // protect LDS before next-chunk DMA
    }
#pragma unroll
    for (int jr = 0; jr < 4; ++jr) {
        size_t r = (size_t)row0 + rg * 4 + jr;
#pragma unroll
        for (int jc = 0; jc < 4; ++jc) {
            int c = cg * 4 + jc;
            if (c < NT) tagL[r * NT + c] = acc[jr][jc] + bt[c];
            else if (c < NT + NP) posL[r * NP + (c - NT)] = acc[jr][jc] + bp[c - NT];
        }
    }
}

// ---------------------------------------------------------------------------
// Kernel 2: the four CRF scans. One wave per (b, role); 256 blocks x 64 thr.
// All-to-all broadcast of the state vector via v_readlane (compile-time lane
// indices); accumulation order kept EXACTLY as the original LDS version so
// results are bitwise unchanged. NLL runs in LINEAR space (f = exp(e)
// precomputed off-chain per chunk; exact power-of-2 rescale per chunk).
// Round-5: the per-chunk max-reduce is now a readlane+fmax tree (VALU-only,
// ~130cy) instead of 6 serial __shfl_xor ds_swizzle round-trips (~700cy on
// a 1-wave block). Max is exact/commutative -> bitwise-identical excorr.
// ---------------------------------------------------------------------------
template <int T, int PAD>
__device__ void nll_scan(int b,
    const float* __restrict__ logits, const int* __restrict__ mask,
    const int* __restrict__ targ, const float* __restrict__ start,
    const float* __restrict__ trans, const float* __restrict__ endv,
    float* __restrict__ den, float* __restrict__ num)
{
    const int lane = threadIdx.x;
    const int jj = (lane < T) ? lane : (T - 1);
    float Ecol[PAD];
#pragma unroll
    for (int i = 0; i < PAD; ++i) Ecol[i] = (i < T) ? __expf(trans[i * T + jj]) : 0.f;
    const float esjj = __expf(start[jj]);
    const float* eptr = logits + (size_t)b * 512 * T + jj;
    const int* mptr = mask + b * 512;

    float eb[CH], en[CH], fb[CH];
    int mb, mn = 0;
#pragma unroll
    for (int k = 0; k < CH; ++k) { eb[k] = eptr[k * T]; en[k] = 0.f; }
    mb = mptr[lane & (CH - 1)];

    float a = 0.f;
    int excorr = 0;
    for (int c = 0; c < 64; ++c) {
        unsigned long long kb = __ballot(mb > 0);
        if (c < 63) {
            const float* ep2 = eptr + (c + 1) * CH * T;
#pragma unroll
            for (int k = 0; k < CH; ++k) en[k] = ep2[k * T];
            mn = mptr[(c + 1) * CH + (lane & (CH - 1))];
        }
#pragma unroll
        for (int k = 0; k < CH; ++k) fb[k] = __expf(eb[k]);   // off-chain
#pragma unroll
        for (int s = 0; s < CH; ++s) {
            // readlane broadcast of a; lanes >= T hold a duplicate of column
            // T-1 and Ecol there is 0, so fma contributes exactly 0.
            float d0 = 0.f, d1 = 0.f, d2 = 0.f, d3 = 0.f;
#pragma unroll
            for (int q = 0; q < PAD / 4; ++q) {
                d0 = fmaf(rlane(a, 4 * q + 0), Ecol[4 * q + 0], d0);
                d1 = fmaf(rlane(a, 4 * q + 1), Ecol[4 * q + 1], d1);
                d2 = fmaf(rlane(a, 4 * q + 2), Ecol[4 * q + 2], d2);
                d3 = fmaf(rlane(a, 4 * q + 3), Ecol[4 * q + 3], d3);
            }
            float cand = ((d0 + d1) + (d2 + d3)) * fb[s];
            bool keep = (kb >> s) & 1ULL;
            bool first = (c == 0) && (s == 0);
            a = first ? (esjj * fb[0]) : (keep ? cand : a);
        }
        // exact power-of-2 rescale; wave-uniform max via readlane tree.
        // Pad lanes mirror lane T-1, so including lanes up to the next
        // multiple of 4 gives the exact same max value.
        float mv0 = rlane(a, 0), mv1 = rlane(a, 1);
        float mv2 = rlane(a, 2), mv3 = rlane(a, 3);
#pragma unroll
        for (int i = 4; i < T; i += 4) {
            mv0 = fmaxf(mv0, rlane(a, i + 0));
            mv1 = fmaxf(mv1, rlane(a, i + 1));
            mv2 = fmaxf(mv2, rlane(a, i + 2));
            mv3 = fmaxf(mv3, rlane(a, i + 3));
        }
        float m = fmaxf(fmaxf(mv0, mv1), fmaxf(mv2, mv3));
        int ex;
        (void)frexpf(m, &ex);
        a *= ldexpf(1.0f, -ex);
        excorr += ex;
#pragma unroll
        for (int k = 0; k < CH; ++k) eb[k] = en[k];
        mb = mn;
    }
    // denominator: log(sum_j a_j * exp(end_j)) + excorr*ln2
    float term = (lane < T) ? a * __expf(endv[lane]) : 0.f;
#pragma unroll
    for (int o = 32; o; o >>= 1) term += __shfl_xor(term, o);
    if (lane == 0) den[b] = __logf(term) + (float)excorr * 0.69314718056f;

    // numerator (raw logits; lse cancels in num-den)
    float part = 0.f; int Lc = 0;
    for (int t = lane; t < 512; t += 64) {
        int mt = mask[b * 512 + t];
        Lc += (mt > 0);
        if (t >= 1 && mt > 0) {
            int tg = targ[b * 512 + t];
            int pg = targ[b * 512 + t - 1];
            part += trans[pg * T + tg] + logits[((size_t)b * 512 + t) * T + tg];
        }
    }
#pragma unroll
    for (int o = 32; o; o >>= 1) { part += __shfl_xor(part, o); Lc += __shfl_xor(Lc, o); }
    if (lane == 0) {
        int t0g = targ[b * 512];
        num[b] = start[t0g] + logits[(size_t)b * 512 * T + t0g]
               + part + endv[targ[b * 512 + Lc - 1]];
    }
}

// Viterbi forward, max only; stores score vectors for later argmax recompute.
// Same readlane broadcast; max is order-exact so scores are bitwise
// unchanged vs the LDS version (hist recompute stays bit-identical).
template <int T, int PAD>
__device__ void vit_fwd(int b,
    const float* __restrict__ logits, const int* __restrict__ mask,
    const float* __restrict__ start, const float* __restrict__ trans,
    float* __restrict__ score)
{
    const int lane = threadIdx.x;
    const int jj = (lane < T) ? lane : (T - 1);
    float Tcol[PAD];
#pragma unroll
    for (int i = 0; i < PAD; ++i) Tcol[i] = (i < T) ? trans[i * T + jj] : -1e30f;
    const float sjj = start[jj];
    const float* eptr = logits + (size_t)b * 512 * T + jj;
    const int* mptr = mask + b * 512;
    float* sptr = score + (size_t)b * 512 * T + lane;

    float eb[CH], en[CH];
    int mb, mn = 0;
#pragma unroll
    for (int k = 0; k < CH; ++k) { eb[k] = eptr[k * T]; en[k] = 0.f; }
    mb = mptr[lane & (CH - 1)];

    float sc = 0.f;
    for (int c = 0; c < 64; ++c) {
        unsigned long long kb = __ballot(mb > 0);
        if (c < 63) {
            const float* ep2 = eptr + (c + 1) * CH * T;
#pragma unroll
            for (int k = 0; k < CH; ++k) en[k] = ep2[k * T];
            mn = mptr[(c + 1) * CH + (lane & (CH - 1))];
        }
#pragma unroll
        for (int s = 0; s < CH; ++s) {
            float m = -1e30f;
#pragma unroll
            for (int q = 0; q < PAD / 4; ++q) {
                float ca = rlane(sc, 4 * q + 0) + Tcol[4 * q + 0];
                float cb = rlane(sc, 4 * q + 1) + Tcol[4 * q + 1];
                float cc = rlane(sc, 4 * q + 2) + Tcol[4 * q + 2];
                float cd = rlane(sc, 4 * q + 3) + Tcol[4 * q + 3];
                m = fmaxf(m, fmaxf(ca, cb));   // -> v_max3
                m = fmaxf(m, fmaxf(cc, cd));
            }
            float nxt = m + eb[s];
            bool keep = (kb >> s) & 1ULL;
            bool first = (c == 0) && (s == 0);
            sc = first ? (sjj + eb[0]) : (keep ? nxt : sc);
            if (lane < T) sptr[(size_t)(c * CH + s) * T] = sc;
        }
#pragma unroll
        for (int k = 0; k < CH; ++k) eb[k] = en[k];
        mb = mn;
    }
}

__global__ __launch_bounds__(64, 1) void scan_kernel(
    const float* tagL, const float* posL, const int* mask,
    const int* tgT, const int* tgP,
    const float* startT, const float* transT, const float* endT,
    const float* startP, const float* transP, const float* endP,
    float* scoreT, float* scoreP,
    float* denT, float* denP, float* numT, float* numP)
{
    int bid = blockIdx.x;
    if (bid < 64)
        vit_fwd<NP, 48>(bid, posL, mask, startP, transP, scoreP);
    else if (bid < 128)
        nll_scan<NP, 48>(bid - 64, posL, mask, tgP, startP, transP, endP, denP, numP);
    else if (bid < 192)
        vit_fwd<NT, 20>(bid - 128, tagL, mask, startT, transT, scoreT);
    else
        nll_scan<NT, 20>(bid - 192, tagL, mask, tgT, startT, transT, endT, denT, numT);
}

// ---------------------------------------------------------------------------
// Kernel 3: recompute Viterbi backpointers massively parallel over (b,t).
// Bit-identical adds vs forward pass => identical argmax.
// ---------------------------------------------------------------------------
template <int T>
__device__ void hist_block(int b, int tc,
    const float* __restrict__ score, const int* __restrict__ mask,
    const float* __restrict__ trans, unsigned char* __restrict__ hist)
{
    const int wave = threadIdx.x >> 6;
    const int lane = threadIdx.x & 63;
    const int jj = (lane < T) ? lane : (T - 1);
    float Tcol[T];
#pragma unroll
    for (int i = 0; i < T; ++i) Tcol[i] = trans[i * T + jj];
    for (int q = 0; q < 16; ++q) {
        int t = tc * 64 + wave * 16 + q;
        if (t < 1) continue;
        int mt = mask[b * 512 + t];
        int hv;
        if (mt > 0) {
            float sv = score[((size_t)b * 512 + t - 1) * T + jj];
            float mx = -1e30f; int am = 0;
#pragma unroll
            for (int i = 0; i < T; ++i) {
                float cand = rlane(sv, i) + Tcol[i];
                bool g = cand > mx;            // strict > keeps FIRST max
                mx = g ? cand : mx;
                am = g ? i : am;
            }
            hv = am;
        } else {
            hv = jj;                           // identity when masked
        }
        if (lane < T)
            hist[((size_t)b * 512 + (t - 1)) * T + lane] = (unsigned char)hv;
    }
}

__global__ __launch_bounds__(256) void hist_kernel(
    const float* scoreT, const float* scoreP, const int* mask,
    const float* transT, const float* transP,
    unsigned char* histT, unsigned char* histP)
{
    int blk = blockIdx.x;
    if (blk < 512) hist_block<NP>(blk >> 3, blk & 7, scoreP, mask, transP, histP);
    else { blk -= 512; hist_block<NT>(blk >> 3, blk & 7, scoreT, mask, transT, histT); }
}

// ---------------------------------------------------------------------------
// Kernel 4: backtrace with pointer-jump composition (serial chain 511 -> 63).
// ---------------------------------------------------------------------------
template <int T>
__device__ void backtrace(int b, const float* __restrict__ score,
    const unsigned char* __restrict__ hist, const float* __restrict__ endv,
    float* __restrict__ outp, unsigned char* sh)
{
    unsigned char* h  = sh;                    // 512*T
    unsigned char* g2 = sh + 512 * T;          // rows 0..509
    unsigned char* g4 = sh + 1024 * T;         // 127 rows (r = 3+4*a4)
    unsigned char* g8 = sh + 1024 * T + 128 * T; // 63 rows (r = 503-8a)
    unsigned char* pr = sh + 1024 * T + 192 * T; // 512
    const int lane = threadIdx.x;

    {   // stage hist to LDS (b-stride = 512*T bytes, 16B multiple)
        const int4* src = (const int4*)(hist + (size_t)b * 512 * T);
        int4* dst = (int4*)h;
        int n16 = (512 * T) / 16;
        for (int i = lane; i < n16; i += 64) dst[i] = src[i];
    }
    __syncthreads();
    // g2[r][i] = h[r][h[r+1][i]]  (maps cur at t=r+2 -> t=r)
    for (int idx = lane; idx < 510 * T; idx += 64) {
        int r = idx / T, i = idx - r * T;
        g2[idx] = h[r * T + h[(r + 1) * T + i]];
    }
    __syncthreads();
    // g4 rows r = 3+4*a4: g4[a4][i] = g2[r][ g2[r+2][i] ]  (t=r+4 -> r)
    for (int idx = lane; idx < 127 * T; idx += 64) {
        int a4 = idx / T, i = idx - a4 * T;
        int r = 3 + 4 * a4;
        g4[idx] = g2[r * T + g2[(r + 2) * T + i]];
    }
    __syncthreads();
    // g8 rows r = 503-8a: g8[a][i] = g4row(r)[ g4row(r+4)[i] ]  (t=r+8 -> r)
    for (int idx = lane; idx < 63 * T; idx += 64) {
        int a = idx / T, i = idx - a * T;
        int r = 503 - 8 * a;
        int a4lo = (r - 3) >> 2, a4hi = (r + 1) >> 2;
        g8[idx] = g4[a4lo * T + g4[a4hi * T + i]];
    }
    // last = first-index argmax(score[511] + end)
    float v = (lane < T) ? (score[((size_t)b * 512 + 511) * T + lane] + endv[lane]) : -1e30f;
    float mx = v;
#pragma unroll
    for (int o = 32; o; o >>= 1) mx = fmaxf(mx, __shfl_xor(mx, o));
    unsigned long long bal = __ballot(v == mx);
    int cur = __ffsll(bal) - 1;
    __syncthreads();
    // phase A: serial anchor chain, 63 dependent LDS reads
    int myCur = 0;
    for (int a = 0; a < 64; ++a) {
        if (lane == a) myCur = cur;
        if (a < 63) cur = g8[a * T + cur];
    }
    // phase B: each lane fills its 8-step segment
    {
        int ta = 511 - 8 * lane;
        int j = myCur;
        pr[ta] = (unsigned char)j;
        int rlo = (lane == 63) ? 0 : (ta - 7);
        for (int r = ta - 1; r >= rlo; --r) {
            j = h[r * T + j];
            pr[r] = (unsigned char)j;
        }
    }
    __syncthreads();
    for (int k = lane; k < 512; k += 64)
        outp[(size_t)b * 512 + k] = (float)pr[k];
}

__global__ __launch_bounds__(64, 1) void backtrace_kernel(
    const float* scoreT, const float* scoreP,
    const unsigned char* histT, const unsigned char* histP,
    const float* endT, const float* endP, float* out)
{
    __shared__ __align__(16) unsigned char sh[1216 * NP + 576];
    int blk = blockIdx.x;
    if (blk < 64) backtrace<NP>(blk, scoreP, histP, endP, out + 32768, sh);
    else backtrace<NT>(blk - 64, scoreT, histT, endT, out, sh);
}

// ---------------------------------------------------------------------------
// Kernel 5: losses = -mean(num - den)
// ---------------------------------------------------------------------------
__global__ __launch_bounds__(64) void finalize_kernel(
    const float* numT, const float* denT, const float* numP, const float* denP,
    float* out)
{
    int lane = threadIdx.x;
    float dT = numT[lane] - denT[lane];
    float dP = numP[lane] - denP[lane];
#pragma unroll
    for (int o = 32; o; o >>= 1) { dT += __shfl_xor(dT, o); dP += __shfl_xor(dP, o); }
    if (lane == 0) {
        out[65536] = -dT / 64.f;
        out[65537] = -dP / 64.f;
    }
}

// ---------------------------------------------------------------------------
extern "C" void kernel_launch(void* const* d_in, const int* in_sizes, int n_in,
                              void* d_out, int out_size, void* d_ws, size_t ws_size,
                              hipStream_t stream)
{
    const float* hidden = (const float*)d_in[0];
    const int*   mask   = (const int*)d_in[1];
    const int*   tgT    = (const int*)d_in[2];
    const int*   tgP    = (const int*)d_in[3];
    const float* Wt     = (const float*)d_in[4];
    const float* bt     = (const float*)d_in[5];
    const float* Wp     = (const float*)d_in[6];
    const float* bp     = (const float*)d_in[7];
    const float* startT = (const float*)d_in[8];
    const float* transT = (const float*)d_in[9];
    const float* endT   = (const float*)d_in[10];
    const float* startP = (const float*)d_in[11];
    const float* transP = (const float*)d_in[12];
    const float* endP   = (const float*)d_in[13];

    float* ws     = (float*)d_ws;
    float* tagL   = ws;                         // 557056
    float* posL   = tagL + 557056;              // 1474560
    float* scoreT = posL + 1474560;             // 557056
    float* scoreP = scoreT + 557056;            // 1474560
    float* denT   = scoreP + 1474560;           // 64
    float* denP   = denT + 64;
    float* numT   = denP + 64;
    float* numP   = numT + 64;
    unsigned char* histT = (unsigned char*)(numP + 64);       // 64*512*17 B
    unsigned char* histP = histT + (size_t)64 * 512 * NT;     // 64*512*45 B
    float* out = (float*)d_out;

    // Wpk (768*64 floats) aliases scoreT: pack_w -> gemm (reads it) strictly
    // precede scan_kernel (which overwrites scoreT). Launch order on the
    // stream guarantees safety; no extra workspace needed.
    float* Wpk = scoreT;

    pack_w<<<192, 256, 0, stream>>>(Wt, Wp, Wpk);
    gemm_logits<<<512, 256, 0, stream>>>(hidden, Wpk, bt, bp, tagL, posL);
    scan_kernel<<<256, 64, 0, stream>>>(tagL, posL, mask, tgT, tgP,
        startT, transT, endT, startP, transP, endP,
        scoreT, scoreP, denT, denP, numT, numP);
    hist_kernel<<<1024, 256, 0, stream>>>(scoreT, scoreP, mask, transT, transP,
        histT, histP);
    backtrace_kernel<<<128, 64, 0, stream>>>(scoreT, scoreP, histT, histP,
        endT, endP, out);
    finalize_kernel<<<1, 64, 0, stream>>>(numT, denT, numP, denP, out);
}

// Round 6
// 405.145 us; speedup vs baseline: 1.5915x; 1.0179x over previous
//
#include <hip/hip_runtime.h>
#include <cmath>
#include <cstdint>
#include <cstddef>

#define NT 17
#define NP 45
#define CH 8
// B=64, S=512, H=768

// Force a value to live in a VGPR: opaque asm blocks rematerialization
// (e.g. per-use reload+exp of trans columns) and scratch demotion.
#define PIN(x) asm volatile("" : "+v"(x))

__device__ __forceinline__ float rlane(float v, int k) {
    return __int_as_float(__builtin_amdgcn_readlane(__float_as_int(v), k));
}

// 16B async global->LDS DMA (no VGPR round-trip, no ds_write instruction).
__device__ __forceinline__ void gload16(const float* g, float* l) {
    __builtin_amdgcn_global_load_lds(
        (const __attribute__((address_space(1))) void*)g,
        (__attribute__((address_space(3))) void*)l, 16, 0, 0);
}

// ---------------------------------------------------------------------------
// Kernel 0: pack W into Wpk[768][64] (17 tag cols | 45 pos cols | 2 zero pad)
// so Bs staging has contiguous 16B-aligned source rows for global_load_lds.
// ---------------------------------------------------------------------------
__global__ __launch_bounds__(256) void pack_w(
    const float* __restrict__ Wt, const float* __restrict__ Wp,
    float* __restrict__ Wpk)
{
    int i = blockIdx.x * 256 + threadIdx.x;
    if (i >= 768 * 64) return;
    int k = i >> 6, c = i & 63;
    float v = 0.f;
    if (c < NT) v = Wt[k * NT + c];
    else if (c < NT + NP) v = Wp[k * NP + (c - NT)];
    Wpk[i] = v;
}

// ---------------------------------------------------------------------------
// Kernel 1: logits = hidden @ [W_tag | W_pos] + bias   (f32 vector GEMM)
// DMA-staged tiles, source-side XOR swizzle on As, zero LDS staging instrs,
// conflict-free reads. Accumulation per output is the identical strictly-
// ascending-k fmaf chain with bias added last -> logits bitwise unchanged.
// ---------------------------------------------------------------------------
__global__ __launch_bounds__(256) void gemm_logits(
    const float* __restrict__ hidden, const float* __restrict__ Wpk,
    const float* __restrict__ bt, const float* __restrict__ bp,
    float* __restrict__ tagL, float* __restrict__ posL)
{
    __shared__ __align__(16) float As[64 * 32];
    __shared__ __align__(16) float Bs[32 * 64];
    const int tid = threadIdx.x;
    const int rg = tid >> 4;          // 0..15 (row group)
    const int cg = tid & 15;          // 0..15 (col group)
    const int srg = rg & 7;
    const int row0 = blockIdx.x * 64;

    float acc[4][4];
#pragma unroll
    for (int a = 0; a < 4; ++a)
#pragma unroll
        for (int b = 0; b < 4; ++b) acc[a][b] = 0.f;

    // staging indices (all dest offsets are tid*16B -> DMA-linear per wave)
    const int arow = tid >> 3;        // 0..31
    const int aq   = tid & 7;         // 0..7  (k-group slot)
    const int bk   = tid >> 4;        // 0..15
    const int bc4  = tid & 15;        // 0..15

#pragma unroll 1
    for (int kc = 0; kc < 768; kc += 32) {
        {   // As rows 0..31 and 32..63: source k-group = slot ^ ((row>>2)&7)
            int r0 = arow;
            int s0 = (r0 >> 2) & 7;
            gload16(hidden + (size_t)(row0 + r0) * 768 + kc + ((aq ^ s0) << 2),
                    As + r0 * 32 + aq * 4);
            int r1 = 32 + arow;
            int s1 = (r1 >> 2) & 7;
            gload16(hidden + (size_t)(row0 + r1) * 768 + kc + ((aq ^ s1) << 2),
                    As + r1 * 32 + aq * 4);
            // Bs rows kc..kc+31 from packed W
            gload16(Wpk + (size_t)(kc + bk) * 64 + bc4 * 4,
                    Bs + bk * 64 + bc4 * 4);
            gload16(Wpk + (size_t)(kc + 16 + bk) * 64 + bc4 * 4,
                    Bs + (16 + bk) * 64 + bc4 * 4);
        }
        __syncthreads();              // implicit vmcnt(0): DMA landed
#pragma unroll
        for (int k4 = 0; k4 < 8; ++k4) {
            const int qb = ((k4 ^ srg) << 2);   // swizzled As slot offset
            float a_[4][4], b_[4][4];
#pragma unroll
            for (int jr = 0; jr < 4; ++jr) {
                float4 t = *(const float4*)(As + (rg * 4 + jr) * 32 + qb);
                a_[jr][0] = t.x; a_[jr][1] = t.y; a_[jr][2] = t.z; a_[jr][3] = t.w;
            }
#pragma unroll
            for (int kk = 0; kk < 4; ++kk) {
                float4 t = *(const float4*)(Bs + (k4 * 4 + kk) * 64 + cg * 4);
                b_[kk][0] = t.x; b_[kk][1] = t.y; b_[kk][2] = t.z; b_[kk][3] = t.w;
            }
#pragma unroll
            for (int kk = 0; kk < 4; ++kk)      // k strictly ascending
#pragma unroll
                for (int jr = 0; jr < 4; ++jr)
#pragma unroll
                    for (int jc = 0; jc < 4; ++jc)
                        acc[jr][jc] = fmaf(a_[jr][kk], b_[kk][jc], acc[jr][jc]);
        }
        __syncthreads();              // protect LDS before next-chunk DMA
    }
#pragma unroll
    for (int jr = 0; jr < 4; ++jr) {
        size_t r = (size_t)row0 + rg * 4 + jr;
#pragma unroll
        for (int jc = 0; jc < 4; ++jc) {
            int c = cg * 4 + jc;
            if (c < NT) tagL[r * NT + c] = acc[jr][jc] + bt[c];
            else if (c < NT + NP) posL[r * NP + (c - NT)] = acc[jr][jc] + bp[c - NT];
        }
    }
}

// ---------------------------------------------------------------------------
// Kernel 2: the four CRF scans. One wave per (b, role); 256 blocks x 64 thr.
// All-to-all broadcast of the state vector via v_readlane (compile-time lane
// indices); accumulation order kept EXACTLY as the original LDS version so
// results are bitwise unchanged. NLL runs in LINEAR space.
// Round-6: the transition columns (Ecol/Tcol) and per-chunk fb are PINned
// into VGPRs. scan VGPR_Count=40 in round 5 proved the compiler was NOT
// keeping these ~90 values resident (scratch spill or per-use remat of
// exp(trans[...])) -- the invariant ~690cy/step across all broadcast
// variants. With launch_bounds(64,1) the budget is 512 VGPRs; pinning
// blocks remat/demotion at zero instruction cost.
// ---------------------------------------------------------------------------
template <int T, int PAD>
__device__ void nll_scan(int b,
    const float* __restrict__ logits, const int* __restrict__ mask,
    const int* __restrict__ targ, const float* __restrict__ start,
    const float* __restrict__ trans, const float* __restrict__ endv,
    float* __restrict__ den, float* __restrict__ num)
{
    const int lane = threadIdx.x;
    const int jj = (lane < T) ? lane : (T - 1);
    float Ecol[PAD];
#pragma unroll
    for (int i = 0; i < PAD; ++i) Ecol[i] = (i < T) ? __expf(trans[i * T + jj]) : 0.f;
#pragma unroll
    for (int i = 0; i < PAD; ++i) PIN(Ecol[i]);
    float esjj = __expf(start[jj]);
    PIN(esjj);
    const float* eptr = logits + (size_t)b * 512 * T + jj;
    const int* mptr = mask + b * 512;

    float eb[CH], en[CH], fb[CH];
    int mb, mn = 0;
#pragma unroll
    for (int k = 0; k < CH; ++k) { eb[k] = eptr[k * T]; en[k] = 0.f; }
    mb = mptr[lane & (CH - 1)];

    float a = 0.f;
    int excorr = 0;
    for (int c = 0; c < 64; ++c) {
        unsigned long long kb = __ballot(mb > 0);
        if (c < 63) {
            const float* ep2 = eptr + (c + 1) * CH * T;
#pragma unroll
            for (int k = 0; k < CH; ++k) en[k] = ep2[k * T];
            mn = mptr[(c + 1) * CH + (lane & (CH - 1))];
        }
#pragma unroll
        for (int k = 0; k < CH; ++k) { fb[k] = __expf(eb[k]); PIN(fb[k]); }
#pragma unroll
        for (int s = 0; s < CH; ++s) {
            // readlane broadcast of a; lanes >= T hold a duplicate of column
            // T-1 and Ecol there is 0, so fma contributes exactly 0.
            float d0 = 0.f, d1 = 0.f, d2 = 0.f, d3 = 0.f;
#pragma unroll
            for (int q = 0; q < PAD / 4; ++q) {
                d0 = fmaf(rlane(a, 4 * q + 0), Ecol[4 * q + 0], d0);
                d1 = fmaf(rlane(a, 4 * q + 1), Ecol[4 * q + 1], d1);
                d2 = fmaf(rlane(a, 4 * q + 2), Ecol[4 * q + 2], d2);
                d3 = fmaf(rlane(a, 4 * q + 3), Ecol[4 * q + 3], d3);
            }
            float cand = ((d0 + d1) + (d2 + d3)) * fb[s];
            bool keep = (kb >> s) & 1ULL;
            bool first = (c == 0) && (s == 0);
            a = first ? (esjj * fb[0]) : (keep ? cand : a);
        }
        // exact power-of-2 rescale; wave-uniform max via readlane tree.
        // Pad lanes mirror lane T-1, so including lanes up to the next
        // multiple of 4 gives the exact same max value.
        float mv0 = rlane(a, 0), mv1 = rlane(a, 1);
        float mv2 = rlane(a, 2), mv3 = rlane(a, 3);
#pragma unroll
        for (int i = 4; i < T; i += 4) {
            mv0 = fmaxf(mv0, rlane(a, i + 0));
            mv1 = fmaxf(mv1, rlane(a, i + 1));
            mv2 = fmaxf(mv2, rlane(a, i + 2));
            mv3 = fmaxf(mv3, rlane(a, i + 3));
        }
        float m = fmaxf(fmaxf(mv0, mv1), fmaxf(mv2, mv3));
        int ex;
        (void)frexpf(m, &ex);
        a *= ldexpf(1.0f, -ex);
        excorr += ex;
#pragma unroll
        for (int k = 0; k < CH; ++k) eb[k] = en[k];
        mb = mn;
    }
    // denominator: log(sum_j a_j * exp(end_j)) + excorr*ln2
    float term = (lane < T) ? a * __expf(endv[lane]) : 0.f;
#pragma unroll
    for (int o = 32; o; o >>= 1) term += __shfl_xor(term, o);
    if (lane == 0) den[b] = __logf(term) + (float)excorr * 0.69314718056f;

    // numerator (raw logits; lse cancels in num-den)
    float part = 0.f; int Lc = 0;
    for (int t = lane; t < 512; t += 64) {
        int mt = mask[b * 512 + t];
        Lc += (mt > 0);
        if (t >= 1 && mt > 0) {
            int tg = targ[b * 512 + t];
            int pg = targ[b * 512 + t - 1];
            part += trans[pg * T + tg] + logits[((size_t)b * 512 + t) * T + tg];
        }
    }
#pragma unroll
    for (int o = 32; o; o >>= 1) { part += __shfl_xor(part, o); Lc += __shfl_xor(Lc, o); }
    if (lane == 0) {
        int t0g = targ[b * 512];
        num[b] = start[t0g] + logits[(size_t)b * 512 * T + t0g]
               + part + endv[targ[b * 512 + Lc - 1]];
    }
}

// Viterbi forward, max only; stores score vectors for later argmax recompute.
// Same readlane broadcast + PINned Tcol; max is order-exact so scores are
// bitwise unchanged (hist recompute stays bit-identical).
template <int T, int PAD>
__device__ void vit_fwd(int b,
    const float* __restrict__ logits, const int* __restrict__ mask,
    const float* __restrict__ start, const float* __restrict__ trans,
    float* __restrict__ score)
{
    const int lane = threadIdx.x;
    const int jj = (lane < T) ? lane : (T - 1);
    float Tcol[PAD];
#pragma unroll
    for (int i = 0; i < PAD; ++i) Tcol[i] = (i < T) ? trans[i * T + jj] : -1e30f;
#pragma unroll
    for (int i = 0; i < PAD; ++i) PIN(Tcol[i]);
    float sjj = start[jj];
    PIN(sjj);
    const float* eptr = logits + (size_t)b * 512 * T + jj;
    const int* mptr = mask + b * 512;
    float* sptr = score + (size_t)b * 512 * T + lane;

    float eb[CH], en[CH];
    int mb, mn = 0;
#pragma unroll
    for (int k = 0; k < CH; ++k) { eb[k] = eptr[k * T]; en[k] = 0.f; }
    mb = mptr[lane & (CH - 1)];

    float sc = 0.f;
    for (int c = 0; c < 64; ++c) {
        unsigned long long kb = __ballot(mb > 0);
        if (c < 63) {
            const float* ep2 = eptr + (c + 1) * CH * T;
#pragma unroll
            for (int k = 0; k < CH; ++k) en[k] = ep2[k * T];
            mn = mptr[(c + 1) * CH + (lane & (CH - 1))];
        }
#pragma unroll
        for (int s = 0; s < CH; ++s) {
            float m = -1e30f;
#pragma unroll
            for (int q = 0; q < PAD / 4; ++q) {
                float ca = rlane(sc, 4 * q + 0) + Tcol[4 * q + 0];
                float cb = rlane(sc, 4 * q + 1) + Tcol[4 * q + 1];
                float cc = rlane(sc, 4 * q + 2) + Tcol[4 * q + 2];
                float cd = rlane(sc, 4 * q + 3) + Tcol[4 * q + 3];
                m = fmaxf(m, fmaxf(ca, cb));   // -> v_max3
                m = fmaxf(m, fmaxf(cc, cd));
            }
            float nxt = m + eb[s];
            bool keep = (kb >> s) & 1ULL;
            bool first = (c == 0) && (s == 0);
            sc = first ? (sjj + eb[0]) : (keep ? nxt : sc);
            if (lane < T) sptr[(size_t)(c * CH + s) * T] = sc;
        }
#pragma unroll
        for (int k = 0; k < CH; ++k) eb[k] = en[k];
        mb = mn;
    }
}

__global__ __launch_bounds__(64, 1) void scan_kernel(
    const float* tagL, const float* posL, const int* mask,
    const int* tgT, const int* tgP,
    const float* startT, const float* transT, const float* endT,
    const float* startP, const float* transP, const float* endP,
    float* scoreT, float* scoreP,
    float* denT, float* denP, float* numT, float* numP)
{
    int bid = blockIdx.x;
    if (bid < 64)
        vit_fwd<NP, 48>(bid, posL, mask, startP, transP, scoreP);
    else if (bid < 128)
        nll_scan<NP, 48>(bid - 64, posL, mask, tgP, startP, transP, endP, denP, numP);
    else if (bid < 192)
        vit_fwd<NT, 20>(bid - 128, tagL, mask, startT, transT, scoreT);
    else
        nll_scan<NT, 20>(bid - 192, tagL, mask, tgT, startT, transT, endT, denT, numT);
}

// ---------------------------------------------------------------------------
// Kernel 3: recompute Viterbi backpointers massively parallel over (b,t).
// Bit-identical adds vs forward pass => identical argmax.
// ---------------------------------------------------------------------------
template <int T>
__device__ void hist_block(int b, int tc,
    const float* __restrict__ score, const int* __restrict__ mask,
    const float* __restrict__ trans, unsigned char* __restrict__ hist)
{
    const int wave = threadIdx.x >> 6;
    const int lane = threadIdx.x & 63;
    const int jj = (lane < T) ? lane : (T - 1);
    float Tcol[T];
#pragma unroll
    for (int i = 0; i < T; ++i) Tcol[i] = trans[i * T + jj];
    for (int q = 0; q < 16; ++q) {
        int t = tc * 64 + wave * 16 + q;
        if (t < 1) continue;
        int mt = mask[b * 512 + t];
        int hv;
        if (mt > 0) {
            float sv = score[((size_t)b * 512 + t - 1) * T + jj];
            float mx = -1e30f; int am = 0;
#pragma unroll
            for (int i = 0; i < T; ++i) {
                float cand = rlane(sv, i) + Tcol[i];
                bool g = cand > mx;            // strict > keeps FIRST max
                mx = g ? cand : mx;
                am = g ? i : am;
            }
            hv = am;
        } else {
            hv = jj;                           // identity when masked
        }
        if (lane < T)
            hist[((size_t)b * 512 + (t - 1)) * T + lane] = (unsigned char)hv;
    }
}

__global__ __launch_bounds__(256) void hist_kernel(
    const float* scoreT, const float* scoreP, const int* mask,
    const float* transT, const float* transP,
    unsigned char* histT, unsigned char* histP)
{
    int blk = blockIdx.x;
    if (blk < 512) hist_block<NP>(blk >> 3, blk & 7, scoreP, mask, transP, histP);
    else { blk -= 512; hist_block<NT>(blk >> 3, blk & 7, scoreT, mask, transT, histT); }
}

// ---------------------------------------------------------------------------
// Kernel 4: backtrace with pointer-jump composition (serial chain 511 -> 63).
// Block 128 additionally computes the losses (was finalize_kernel; merged
// to save one launch).
// ---------------------------------------------------------------------------
template <int T>
__device__ void backtrace(int b, const float* __restrict__ score,
    const unsigned char* __restrict__ hist, const float* __restrict__ endv,
    float* __restrict__ outp, unsigned char* sh)
{
    unsigned char* h  = sh;                    // 512*T
    unsigned char* g2 = sh + 512 * T;          // rows 0..509
    unsigned char* g4 = sh + 1024 * T;         // 127 rows (r = 3+4*a4)
    unsigned char* g8 = sh + 1024 * T + 128 * T; // 63 rows (r = 503-8a)
    unsigned char* pr = sh + 1024 * T + 192 * T; // 512
    const int lane = threadIdx.x;

    {   // stage hist to LDS (b-stride = 512*T bytes, 16B multiple)
        const int4* src = (const int4*)(hist + (size_t)b * 512 * T);
        int4* dst = (int4*)h;
        int n16 = (512 * T) / 16;
        for (int i = lane; i < n16; i += 64) dst[i] = src[i];
    }
    __syncthreads();
    // g2[r][i] = h[r][h[r+1][i]]  (maps cur at t=r+2 -> t=r)
    for (int idx = lane; idx < 510 * T; idx += 64) {
        int r = idx / T, i = idx - r * T;
        g2[idx] = h[r * T + h[(r + 1) * T + i]];
    }
    __syncthreads();
    // g4 rows r = 3+4*a4: g4[a4][i] = g2[r][ g2[r+2][i] ]  (t=r+4 -> r)
    for (int idx = lane; idx < 127 * T; idx += 64) {
        int a4 = idx / T, i = idx - a4 * T;
        int r = 3 + 4 * a4;
        g4[idx] = g2[r * T + g2[(r + 2) * T + i]];
    }
    __syncthreads();
    // g8 rows r = 503-8a: g8[a][i] = g4row(r)[ g4row(r+4)[i] ]  (t=r+8 -> r)
    for (int idx = lane; idx < 63 * T; idx += 64) {
        int a = idx / T, i = idx - a * T;
        int r = 503 - 8 * a;
        int a4lo = (r - 3) >> 2, a4hi = (r + 1) >> 2;
        g8[idx] = g4[a4lo * T + g4[a4hi * T + i]];
    }
    // last = first-index argmax(score[511] + end)
    float v = (lane < T) ? (score[((size_t)b * 512 + 511) * T + lane] + endv[lane]) : -1e30f;
    float mx = v;
#pragma unroll
    for (int o = 32; o; o >>= 1) mx = fmaxf(mx, __shfl_xor(mx, o));
    unsigned long long bal = __ballot(v == mx);
    int cur = __ffsll(bal) - 1;
    __syncthreads();
    // phase A: serial anchor chain, 63 dependent LDS reads
    int myCur = 0;
    for (int a = 0; a < 64; ++a) {
        if (lane == a) myCur = cur;
        if (a < 63) cur = g8[a * T + cur];
    }
    // phase B: each lane fills its 8-step segment
    {
        int ta = 511 - 8 * lane;
        int j = myCur;
        pr[ta] = (unsigned char)j;
        int rlo = (lane == 63) ? 0 : (ta - 7);
        for (int r = ta - 1; r >= rlo; --r) {
            j = h[r * T + j];
            pr[r] = (unsigned char)j;
        }
    }
    __syncthreads();
    for (int k = lane; k < 512; k += 64)
        outp[(size_t)b * 512 + k] = (float)pr[k];
}

__global__ __launch_bounds__(64, 1) void backtrace_kernel(
    const float* scoreT, const float* scoreP,
    const unsigned char* histT, const unsigned char* histP,
    const float* endT, const float* endP,
    const float* numT, const float* denT,
    const float* numP, const float* denP, float* out)
{
    __shared__ __align__(16) unsigned char sh[1216 * NP + 576];
    int blk = blockIdx.x;
    if (blk < 64) backtrace<NP>(blk, scoreP, histP, endP, out + 32768, sh);
    else if (blk < 128) backtrace<NT>(blk - 64, scoreT, histT, endT, out, sh);
    else {
        // merged finalize: losses = -mean(num - den)
        int lane = threadIdx.x;
        float dT = numT[lane] - denT[lane];
        float dP = numP[lane] - denP[lane];
#pragma unroll
        for (int o = 32; o; o >>= 1) { dT += __shfl_xor(dT, o); dP += __shfl_xor(dP, o); }
        if (lane == 0) {
            out[65536] = -dT / 64.f;
            out[65537] = -dP / 64.f;
        }
    }
}

// ---------------------------------------------------------------------------
extern "C" void kernel_launch(void* const* d_in, const int* in_sizes, int n_in,
                              void* d_out, int out_size, void* d_ws, size_t ws_size,
                              hipStream_t stream)
{
    const float* hidden = (const float*)d_in[0];
    const int*   mask   = (const int*)d_in[1];
    const int*   tgT    = (const int*)d_in[2];
    const int*   tgP    = (const int*)d_in[3];
    const float* Wt     = (const float*)d_in[4];
    const float* bt     = (const float*)d_in[5];
    const float* Wp     = (const float*)d_in[6];
    const float* bp     = (const float*)d_in[7];
    const float* startT = (const float*)d_in[8];
    const float* transT = (const float*)d_in[9];
    const float* endT   = (const float*)d_in[10];
    const float* startP = (const float*)d_in[11];
    const float* transP = (const float*)d_in[12];
    const float* endP   = (const float*)d_in[13];

    float* ws     = (float*)d_ws;
    float* tagL   = ws;                         // 557056
    float* posL   = tagL + 557056;              // 1474560
    float* scoreT = posL + 1474560;             // 557056
    float* scoreP = scoreT + 557056;            // 1474560
    float* denT   = scoreP + 1474560;           // 64
    float* denP   = denT + 64;
    float* numT   = denP + 64;
    float* numP   = numT + 64;
    unsigned char* histT = (unsigned char*)(numP + 64);       // 64*512*17 B
    unsigned char* histP = histT + (size_t)64 * 512 * NT;     // 64*512*45 B
    float* out = (float*)d_out;

    // Wpk (768*64 floats) aliases scoreT: pack_w -> gemm (reads it) strictly
    // precede scan_kernel (which overwrites scoreT). Launch order on the
    // stream guarantees safety; no extra workspace needed.
    float* Wpk = scoreT;

    pack_w<<<192, 256, 0, stream>>>(Wt, Wp, Wpk);
    gemm_logits<<<512, 256, 0, stream>>>(hidden, Wpk, bt, bp, tagL, posL);
    scan_kernel<<<256, 64, 0, stream>>>(tagL, posL, mask, tgT, tgP,
        startT, transT, endT, startP, transP, endP,
        scoreT, scoreP, denT, denP, numT, numP);
    hist_kernel<<<1024, 256, 0, stream>>>(scoreT, scoreP, mask, transT, transP,
        histT, histP);
    backtrace_kernel<<<129, 64, 0, stream>>>(scoreT, scoreP, histT, histP,
        endT, endP, numT, denT, numP, denP, out);
}